// Round 4
// baseline (359.311 us; speedup 1.0000x reference)
//
#include <hip/hip_runtime.h>
#include <hip/hip_bf16.h>

typedef __attribute__((ext_vector_type(8))) short bf16x8;
typedef __attribute__((ext_vector_type(4))) float f32x4;
typedef __hip_bfloat16 bf16;

#define BATCH 8
#define SEQ   2048
#define DMODEL 512
#define DHEAD 64
#define ROWS (BATCH * SEQ)
#define LOG2E 1.44269504f

static __device__ inline short f2bf(float f) {
    union { __hip_bfloat16 h; short s; } u;
    u.h = __float2bfloat16(f);
    return u.s;
}

// ---------------------------------------------------------------------------
// W transpose: w[512][64] fp32 -> wt[64][512] bf16, LDS-tiled, coalesced both
// sides. grid (3 sel x 8 k-tiles) = 24 blocks, block 256.
__global__ __launch_bounds__(256) void transpose_w_kernel(
    const float* __restrict__ wq, const float* __restrict__ wk,
    const float* __restrict__ wv, bf16* __restrict__ wt)
{
    const int s  = blockIdx.x / 8;       // 0:wq 1:wk 2:wv
    const int kt = blockIdx.x % 8;       // k-tile of 64
    const float* w = (s == 0) ? wq : ((s == 1) ? wk : wv);

    __shared__ float Ts[64][68];         // [k][n], +4 pad

    const int tid = threadIdx.x;
    int nr = tid >> 4;                   // 0..15
    int n4 = (tid & 15) * 4;
#pragma unroll
    for (int p = 0; p < 4; ++p) {
        int k = 16 * p + nr;
        float4 v = *(const float4*)(w + (size_t)(kt * 64 + k) * DHEAD + n4);
        Ts[k][n4] = v.x; Ts[k][n4 + 1] = v.y; Ts[k][n4 + 2] = v.z; Ts[k][n4 + 3] = v.w;
    }
    __syncthreads();
#pragma unroll
    for (int p = 0; p < 2; ++p) {
        int cc = tid + p * 256;          // 0..511
        int n = cc >> 3;
        int kk = (cc & 7) * 8;
        bf16x8 o;
#pragma unroll
        for (int e = 0; e < 8; ++e) o[e] = f2bf(Ts[kk + e][n]);
        *(bf16x8*)(wt + (size_t)(s * 64 + n) * DMODEL + kt * 64 + kk) = o;
    }
}

// ---------------------------------------------------------------------------
// Fused QKV projection. grid ROWS/32 = 512 blocks, block 512 (8 waves).
__global__ __launch_bounds__(512) void proj_kernel(
    const float* __restrict__ x, const bf16* __restrict__ wt,
    bf16* __restrict__ Q, bf16* __restrict__ K, bf16* __restrict__ Vt)
{
    const int r0 = blockIdx.x * 32;
    const int tid = threadIdx.x;
    const int lane = tid & 63;
    const int wid = tid >> 6;          // 0..7
    const int strip = wid & 1;
    const int cq = wid >> 1;           // 0..3
    const int l15 = lane & 15;
    const int quad = lane >> 4;

    f32x4 acc[3] = {};

    const float* xp = x + (size_t)(r0 + 16 * strip + l15) * DMODEL;

    for (int k0 = 0; k0 < DMODEL; k0 += 64) {
        float4 xa = *(const float4*)(xp + k0 + quad * 8);
        float4 xb = *(const float4*)(xp + k0 + quad * 8 + 4);
        float4 xc = *(const float4*)(xp + k0 + 32 + quad * 8);
        float4 xd = *(const float4*)(xp + k0 + 32 + quad * 8 + 4);
        bf16x8 a0, a1;
        a0[0] = f2bf(xa.x); a0[1] = f2bf(xa.y); a0[2] = f2bf(xa.z); a0[3] = f2bf(xa.w);
        a0[4] = f2bf(xb.x); a0[5] = f2bf(xb.y); a0[6] = f2bf(xb.z); a0[7] = f2bf(xb.w);
        a1[0] = f2bf(xc.x); a1[1] = f2bf(xc.y); a1[2] = f2bf(xc.z); a1[3] = f2bf(xc.w);
        a1[4] = f2bf(xd.x); a1[5] = f2bf(xd.y); a1[6] = f2bf(xd.z); a1[7] = f2bf(xd.w);
#pragma unroll
        for (int g = 0; g < 3; ++g) {
            int n = 16 * (3 * cq + g) + l15;
            const bf16* wp = wt + (size_t)n * DMODEL + k0 + quad * 8;
            bf16x8 b0 = *(const bf16x8*)(wp);
            bf16x8 b1 = *(const bf16x8*)(wp + 32);
            acc[g] = __builtin_amdgcn_mfma_f32_16x16x32_bf16(a0, b0, acc[g], 0, 0, 0);
            acc[g] = __builtin_amdgcn_mfma_f32_16x16x32_bf16(a1, b1, acc[g], 0, 0, 0);
        }
    }

#pragma unroll
    for (int g = 0; g < 3; ++g) {
        int ng = 16 * (3 * cq + g) + l15;   // 0..191
        int sel = ng >> 6;
        int col = ng & 63;
#pragma unroll
        for (int r = 0; r < 4; ++r) {
            int row = r0 + 16 * strip + quad * 4 + r;   // flat (b*SEQ + i)
            union { __hip_bfloat16 h; bf16 b; } u;
            u.h = __float2bfloat16(acc[g][r]);
            if (sel == 0)      Q[(size_t)row * DHEAD + col] = u.b;
            else if (sel == 1) K[(size_t)row * DHEAD + col] = u.b;
            else {
                int bb = row >> 11, j = row & (SEQ - 1);
                Vt[((size_t)bb * DHEAD + col) * SEQ + j] = u.b;
            }
        }
    }
}

// ---------------------------------------------------------------------------
// Flash attention, single-pass mask, register-pipelined (distance 1).
// 4-way contiguous j-split, ZERO barriers in the K-loop.
//
// Per round, per wave: mask ints for round kk+1 are loaded into v[16]
// registers AFTER the K loads (in-order vmcnt: QK^T's K-wait is vmcnt(16),
// leaving the mask in flight) and consumed a FULL ROUND later via __ballot
// (wave64 ballot IS the 64-bit pack; wave-uniform, selected per-quad).
// sched_barrier(0) after K-load issuance pins the K-before-mask issue order
// so the scheduler cannot hoist mask loads above K (which would turn the
// K-wait into a full drain — R3's mistake).
__global__ __launch_bounds__(256) void flash_kernel(
    const bf16* __restrict__ Q, const bf16* __restrict__ K,
    const bf16* __restrict__ Vt, const int* __restrict__ mask,
    float* __restrict__ out)
{
    const int b = blockIdx.y;
    const int q0 = blockIdx.x * 16;
    const int tid = threadIdx.x;
    const int lane = tid & 63;
    const int wid = tid >> 6;      // 0..3 = j-split index
    const int l15 = lane & 15;
    const int quad = lane >> 4;

    __shared__ __align__(16) bf16 Ps[4][16][72];    // wave-private P tiles
    __shared__ float Om[4][16][64];                 // partial O per wave
    __shared__ float Mw[4][16];                     // partial m per wave
    __shared__ float Lw[4][16];                     // partial l per wave

    const bf16* qp = Q + ((size_t)(b * SEQ + q0 + l15)) * DHEAD + quad * 8;
    bf16x8 aQ0 = *(const bf16x8*)(qp);
    bf16x8 aQ1 = *(const bf16x8*)(qp + 32);

    f32x4 oacc[4] = {};
    float m_i[4], l_i[4];
#pragma unroll
    for (int r = 0; r < 4; ++r) { m_i[r] = -1e30f; l_i[r] = 0.f; }

    const int jbase = wid * (SEQ / 4);
    // wave-local mask base: 16 rows, this wave's j-range
    const int* mrow0 = mask + ((size_t)(b * SEQ + q0)) * SEQ + jbase;

    // prologue: round-0 mask ints (one exposed latency, once)
    int v[16];
#pragma unroll
    for (int i = 0; i < 16; ++i) v[i] = mrow0[(size_t)i * SEQ + lane];

    for (int kk = 0; kk < 8; ++kk) {
        const int j0 = jbase + kk * 64;

        // pack THIS round's mask from v (loads are a full round old -> free)
        unsigned long long bal[16];
#pragma unroll
        for (int i = 0; i < 16; ++i) bal[i] = __ballot(v[i] != 0);
        unsigned long long mrw[4];
#pragma unroll
        for (int r = 0; r < 4; ++r) {
            unsigned long long b01 = (quad & 1) ? bal[4 + r]  : bal[r];
            unsigned long long b23 = (quad & 1) ? bal[12 + r] : bal[8 + r];
            mrw[r] = ((quad & 2) ? b23 : b01) >> l15;
        }

        // K loads FIRST (L2-resident, short latency)
        bf16x8 kb[8];
#pragma unroll
        for (int c = 0; c < 4; ++c) {
            const bf16* kp = K + ((size_t)(b * SEQ + j0 + 16 * c + l15)) * DHEAD + quad * 8;
            kb[2 * c]     = *(const bf16x8*)(kp);
            kb[2 * c + 1] = *(const bf16x8*)(kp + 32);
        }
        __builtin_amdgcn_sched_barrier(0);   // pin: mask loads stay AFTER K loads

        // issue NEXT round's mask loads (consumed next iteration)
        if (kk < 7) {
#pragma unroll
            for (int i = 0; i < 16; ++i)
                v[i] = mrow0[(size_t)i * SEQ + (kk + 1) * 64 + lane];
        }

        // S = Q K^T (C layout: row q = quad*4+r, col j = 16c+l15)
        // K-wait here is a counted vmcnt -> the 16 mask loads stay in flight
        f32x4 sacc[4] = {};
#pragma unroll
        for (int c = 0; c < 4; ++c) {
            sacc[c] = __builtin_amdgcn_mfma_f32_16x16x32_bf16(aQ0, kb[2 * c],     sacc[c], 0, 0, 0);
            sacc[c] = __builtin_amdgcn_mfma_f32_16x16x32_bf16(aQ1, kb[2 * c + 1], sacc[c], 0, 0, 0);
        }

        // scale + mask: after >>l15 the 4 bits sit at positions 0,16,32,48
#pragma unroll
        for (int r = 0; r < 4; ++r) {
            unsigned m0 = (unsigned)mrw[r];
            unsigned m1 = (unsigned)(mrw[r] >> 32);
            sacc[0][r] = (m0 & 1u)         ? sacc[0][r] * 0.125f : -1e30f;
            sacc[1][r] = ((m0 >> 16) & 1u) ? sacc[1][r] * 0.125f : -1e30f;
            sacc[2][r] = (m1 & 1u)         ? sacc[2][r] * 0.125f : -1e30f;
            sacc[3][r] = ((m1 >> 16) & 1u) ? sacc[3][r] * 0.125f : -1e30f;
        }

        // online softmax (row r lives on the 16 lanes of this quad)
#pragma unroll
        for (int r = 0; r < 4; ++r) {
            float rm = fmaxf(fmaxf(sacc[0][r], sacc[1][r]), fmaxf(sacc[2][r], sacc[3][r]));
            rm = fmaxf(rm, __shfl_xor(rm, 1));
            rm = fmaxf(rm, __shfl_xor(rm, 2));
            rm = fmaxf(rm, __shfl_xor(rm, 4));
            rm = fmaxf(rm, __shfl_xor(rm, 8));
            float mn = fmaxf(m_i[r], rm);
            float alpha = exp2f((m_i[r] - mn) * LOG2E);
            m_i[r] = mn;
            float rs = 0.f;
#pragma unroll
            for (int c = 0; c < 4; ++c) {
                float pv = exp2f((sacc[c][r] - mn) * LOG2E);
                sacc[c][r] = pv;
                rs += pv;
            }
            rs += __shfl_xor(rs, 1);
            rs += __shfl_xor(rs, 2);
            rs += __shfl_xor(rs, 4);
            rs += __shfl_xor(rs, 8);
            l_i[r] = l_i[r] * alpha + rs;
#pragma unroll
            for (int c = 0; c < 4; ++c) oacc[c][r] *= alpha;
        }

        // P: C-layout -> A-layout via wave-private LDS (no barrier needed)
#pragma unroll
        for (int c = 0; c < 4; ++c)
#pragma unroll
            for (int r = 0; r < 4; ++r) {
                union { __hip_bfloat16 h; bf16 b; } u;
                u.h = __float2bfloat16(sacc[c][r]);
                Ps[wid][quad * 4 + r][16 * c + l15] = u.b;
            }

        bf16x8 aP0 = *(const bf16x8*)(&Ps[wid][l15][quad * 8]);
        bf16x8 aP1 = *(const bf16x8*)(&Ps[wid][l15][32 + quad * 8]);
#pragma unroll
        for (int c = 0; c < 4; ++c) {
            const bf16* vp = Vt + ((size_t)b * DHEAD + 16 * c + l15) * SEQ + j0 + quad * 8;
            bf16x8 v0 = *(const bf16x8*)(vp);
            bf16x8 v1 = *(const bf16x8*)(vp + 32);
            oacc[c] = __builtin_amdgcn_mfma_f32_16x16x32_bf16(aP0, v0, oacc[c], 0, 0, 0);
            oacc[c] = __builtin_amdgcn_mfma_f32_16x16x32_bf16(aP1, v1, oacc[c], 0, 0, 0);
        }
    }

    // stash partials
#pragma unroll
    for (int c = 0; c < 4; ++c)
#pragma unroll
        for (int r = 0; r < 4; ++r)
            Om[wid][quad * 4 + r][16 * c + l15] = oacc[c][r];
    if (l15 == 0) {
#pragma unroll
        for (int r = 0; r < 4; ++r) {
            Mw[wid][quad * 4 + r] = m_i[r];
            Lw[wid][quad * 4 + r] = l_i[r];
        }
    }
    __syncthreads();

    // combine: 256 threads, 4 output floats each (16 rows x 64 cols)
    {
        int row = tid >> 4;
        int c0 = (tid & 15) * 4;
        float M = fmaxf(fmaxf(Mw[0][row], Mw[1][row]), fmaxf(Mw[2][row], Mw[3][row]));
        float sc0 = exp2f((Mw[0][row] - M) * LOG2E);
        float sc1 = exp2f((Mw[1][row] - M) * LOG2E);
        float sc2 = exp2f((Mw[2][row] - M) * LOG2E);
        float sc3 = exp2f((Mw[3][row] - M) * LOG2E);
        float L = Lw[0][row] * sc0 + Lw[1][row] * sc1 + Lw[2][row] * sc2 + Lw[3][row] * sc3;
        float invL = 1.0f / L;
        float4 o;
        float* op = (float*)&o;
#pragma unroll
        for (int e = 0; e < 4; ++e) {
            op[e] = (Om[0][row][c0 + e] * sc0 + Om[1][row][c0 + e] * sc1 +
                     Om[2][row][c0 + e] * sc2 + Om[3][row][c0 + e] * sc3) * invL;
        }
        *(float4*)(out + ((size_t)(b * SEQ + q0 + row)) * DHEAD + c0) = o;
    }
}

extern "C" void kernel_launch(void* const* d_in, const int* in_sizes, int n_in,
                              void* d_out, int out_size, void* d_ws, size_t ws_size,
                              hipStream_t stream)
{
    // setup_inputs order: mask, x_key_value, wk, wq, wv   (wk BEFORE wq!)
    const int*   mask = (const int*)d_in[0];
    const float* x    = (const float*)d_in[1];
    const float* wk   = (const float*)d_in[2];
    const float* wq   = (const float*)d_in[3];
    const float* wv   = (const float*)d_in[4];
    float* out = (float*)d_out;

    bf16* Qb = (bf16*)d_ws;
    bf16* Kb = Qb + (size_t)ROWS * DHEAD;
    bf16* Vt = Kb + (size_t)ROWS * DHEAD;
    bf16* Wt = Vt + (size_t)BATCH * DHEAD * SEQ;

    transpose_w_kernel<<<dim3(24), 256, 0, stream>>>(wq, wk, wv, Wt);
    proj_kernel<<<dim3(ROWS / 32), 512, 0, stream>>>(x, Wt, Qb, Kb, Vt);
    flash_kernel<<<dim3(SEQ / 16, BATCH), 256, 0, stream>>>(Qb, Kb, Vt, mask, out);
}

// Round 5
// 285.814 us; speedup vs baseline: 1.2571x; 1.2571x over previous
//
#include <hip/hip_runtime.h>
#include <hip/hip_bf16.h>

typedef __attribute__((ext_vector_type(8))) short bf16x8;
typedef __attribute__((ext_vector_type(4))) float f32x4;
typedef __hip_bfloat16 bf16;

#define BATCH 8
#define SEQ   2048
#define DMODEL 512
#define DHEAD 64
#define ROWS (BATCH * SEQ)
#define LOG2E 1.44269504f

static __device__ inline short f2bf(float f) {
    union { __hip_bfloat16 h; short s; } u;
    u.h = __float2bfloat16(f);
    return u.s;
}

// ---------------------------------------------------------------------------
// W transpose: w[512][64] fp32 -> wt[64][512] bf16, LDS-tiled, coalesced both
// sides. grid (3 sel x 8 k-tiles) = 24 blocks, block 256.
__global__ __launch_bounds__(256) void transpose_w_kernel(
    const float* __restrict__ wq, const float* __restrict__ wk,
    const float* __restrict__ wv, bf16* __restrict__ wt)
{
    const int s  = blockIdx.x / 8;       // 0:wq 1:wk 2:wv
    const int kt = blockIdx.x % 8;       // k-tile of 64
    const float* w = (s == 0) ? wq : ((s == 1) ? wk : wv);

    __shared__ float Ts[64][68];         // [k][n], +4 pad

    const int tid = threadIdx.x;
    int nr = tid >> 4;                   // 0..15
    int n4 = (tid & 15) * 4;
#pragma unroll
    for (int p = 0; p < 4; ++p) {
        int k = 16 * p + nr;
        float4 v = *(const float4*)(w + (size_t)(kt * 64 + k) * DHEAD + n4);
        Ts[k][n4] = v.x; Ts[k][n4 + 1] = v.y; Ts[k][n4 + 2] = v.z; Ts[k][n4 + 3] = v.w;
    }
    __syncthreads();
#pragma unroll
    for (int p = 0; p < 2; ++p) {
        int cc = tid + p * 256;          // 0..511
        int n = cc >> 3;
        int kk = (cc & 7) * 8;
        bf16x8 o;
#pragma unroll
        for (int e = 0; e < 8; ++e) o[e] = f2bf(Ts[kk + e][n]);
        *(bf16x8*)(wt + (size_t)(s * 64 + n) * DMODEL + kt * 64 + kk) = o;
    }
}

// ---------------------------------------------------------------------------
// Fused QKV projection. grid ROWS/32 = 512 blocks, block 512 (8 waves).
__global__ __launch_bounds__(512) void proj_kernel(
    const float* __restrict__ x, const bf16* __restrict__ wt,
    bf16* __restrict__ Q, bf16* __restrict__ K, bf16* __restrict__ Vt)
{
    const int r0 = blockIdx.x * 32;
    const int tid = threadIdx.x;
    const int lane = tid & 63;
    const int wid = tid >> 6;          // 0..7
    const int strip = wid & 1;
    const int cq = wid >> 1;           // 0..3
    const int l15 = lane & 15;
    const int quad = lane >> 4;

    f32x4 acc[3] = {};

    const float* xp = x + (size_t)(r0 + 16 * strip + l15) * DMODEL;

    for (int k0 = 0; k0 < DMODEL; k0 += 64) {
        float4 xa = *(const float4*)(xp + k0 + quad * 8);
        float4 xb = *(const float4*)(xp + k0 + quad * 8 + 4);
        float4 xc = *(const float4*)(xp + k0 + 32 + quad * 8);
        float4 xd = *(const float4*)(xp + k0 + 32 + quad * 8 + 4);
        bf16x8 a0, a1;
        a0[0] = f2bf(xa.x); a0[1] = f2bf(xa.y); a0[2] = f2bf(xa.z); a0[3] = f2bf(xa.w);
        a0[4] = f2bf(xb.x); a0[5] = f2bf(xb.y); a0[6] = f2bf(xb.z); a0[7] = f2bf(xb.w);
        a1[0] = f2bf(xc.x); a1[1] = f2bf(xc.y); a1[2] = f2bf(xc.z); a1[3] = f2bf(xc.w);
        a1[4] = f2bf(xd.x); a1[5] = f2bf(xd.y); a1[6] = f2bf(xd.z); a1[7] = f2bf(xd.w);
#pragma unroll
        for (int g = 0; g < 3; ++g) {
            int n = 16 * (3 * cq + g) + l15;
            const bf16* wp = wt + (size_t)n * DMODEL + k0 + quad * 8;
            bf16x8 b0 = *(const bf16x8*)(wp);
            bf16x8 b1 = *(const bf16x8*)(wp + 32);
            acc[g] = __builtin_amdgcn_mfma_f32_16x16x32_bf16(a0, b0, acc[g], 0, 0, 0);
            acc[g] = __builtin_amdgcn_mfma_f32_16x16x32_bf16(a1, b1, acc[g], 0, 0, 0);
        }
    }

#pragma unroll
    for (int g = 0; g < 3; ++g) {
        int ng = 16 * (3 * cq + g) + l15;   // 0..191
        int sel = ng >> 6;
        int col = ng & 63;
#pragma unroll
        for (int r = 0; r < 4; ++r) {
            int row = r0 + 16 * strip + quad * 4 + r;   // flat (b*SEQ + i)
            union { __hip_bfloat16 h; bf16 b; } u;
            u.h = __float2bfloat16(acc[g][r]);
            if (sel == 0)      Q[(size_t)row * DHEAD + col] = u.b;
            else if (sel == 1) K[(size_t)row * DHEAD + col] = u.b;
            else {
                int bb = row >> 11, j = row & (SEQ - 1);
                Vt[((size_t)bb * DHEAD + col) * SEQ + j] = u.b;
            }
        }
    }
}

// ---------------------------------------------------------------------------
// Flash attention, single-pass mask, register-pipelined (distance 1).
// 4-way contiguous j-split, ZERO barriers in the K-loop.
//
// Round structure: ballot-pack THIS round's mask from v[16] (loaded last
// round, already complete) -> K loads -> sched_barrier(0) -> issue NEXT
// round's mask loads -> QK^T (K-wait is counted; mask loads stay in flight)
// -> mask+softmax -> P -> PV (V-wait drains the mask loads, ~600 cyc after
// issue). No arrays with runtime-index-fusible access patterns: the R4
// scratch blowup (WRITE_SIZE 226 MB) came from `(quad&1)? bal[4+r]: bal[r]`
// being canonicalized to bal[runtime] -> local memory. All ballot temps are
// named scalars now; only statically-indexed v[16]/mrw[4] remain (proven
// safe in R3: WRITE_SIZE 4 MB).
__global__ __launch_bounds__(256) void flash_kernel(
    const bf16* __restrict__ Q, const bf16* __restrict__ K,
    const bf16* __restrict__ Vt, const int* __restrict__ mask,
    float* __restrict__ out)
{
    const int b = blockIdx.y;
    const int q0 = blockIdx.x * 16;
    const int tid = threadIdx.x;
    const int lane = tid & 63;
    const int wid = tid >> 6;      // 0..3 = j-split index
    const int l15 = lane & 15;
    const int quad = lane >> 4;

    __shared__ __align__(16) bf16 Ps[4][16][72];    // wave-private P tiles
    __shared__ float Om[4][16][64];                 // partial O per wave
    __shared__ float Mw[4][16];                     // partial m per wave
    __shared__ float Lw[4][16];                     // partial l per wave

    const bf16* qp = Q + ((size_t)(b * SEQ + q0 + l15)) * DHEAD + quad * 8;
    bf16x8 aQ0 = *(const bf16x8*)(qp);
    bf16x8 aQ1 = *(const bf16x8*)(qp + 32);

    f32x4 oacc[4] = {};
    float m_i[4], l_i[4];
#pragma unroll
    for (int r = 0; r < 4; ++r) { m_i[r] = -1e30f; l_i[r] = 0.f; }

    const int jbase = wid * (SEQ / 4);
    // wave-local mask base: 16 rows, this wave's j-range
    const int* mrow0 = mask + ((size_t)(b * SEQ + q0)) * SEQ + jbase;

    // prologue: round-0 mask ints (one exposed latency, once)
    int v[16];
#pragma unroll
    for (int i = 0; i < 16; ++i) v[i] = mrow0[(size_t)i * SEQ + lane];

    for (int kk = 0; kk < 8; ++kk) {
        const int j0 = jbase + kk * 64;

        // pack THIS round's mask from v. Named scalar ballots + cndmask on
        // scalars only (quad*4+r selection) — no array the compiler can turn
        // into a runtime-indexed (scratch) access.
        unsigned long long mrw[4];
#pragma unroll
        for (int r = 0; r < 4; ++r) {
            unsigned long long b0 = __ballot(v[r]      != 0);
            unsigned long long b1 = __ballot(v[4 + r]  != 0);
            unsigned long long b2 = __ballot(v[8 + r]  != 0);
            unsigned long long b3 = __ballot(v[12 + r] != 0);
            unsigned long long s01 = (quad & 1) ? b1 : b0;
            unsigned long long s23 = (quad & 1) ? b3 : b2;
            mrw[r] = ((quad & 2) ? s23 : s01) >> l15;
        }

        // K loads FIRST (L2-resident, short latency)
        bf16x8 kb[8];
#pragma unroll
        for (int c = 0; c < 4; ++c) {
            const bf16* kp = K + ((size_t)(b * SEQ + j0 + 16 * c + l15)) * DHEAD + quad * 8;
            kb[2 * c]     = *(const bf16x8*)(kp);
            kb[2 * c + 1] = *(const bf16x8*)(kp + 32);
        }
        __builtin_amdgcn_sched_barrier(0);   // pin: mask loads stay AFTER K loads

        // issue NEXT round's mask loads (consumed next iteration)
        if (kk < 7) {
#pragma unroll
            for (int i = 0; i < 16; ++i)
                v[i] = mrow0[(size_t)i * SEQ + (kk + 1) * 64 + lane];
        }

        // S = Q K^T (C layout: row q = quad*4+r, col j = 16c+l15)
        // K-wait here is a counted vmcnt -> the 16 mask loads stay in flight
        f32x4 sacc[4] = {};
#pragma unroll
        for (int c = 0; c < 4; ++c) {
            sacc[c] = __builtin_amdgcn_mfma_f32_16x16x32_bf16(aQ0, kb[2 * c],     sacc[c], 0, 0, 0);
            sacc[c] = __builtin_amdgcn_mfma_f32_16x16x32_bf16(aQ1, kb[2 * c + 1], sacc[c], 0, 0, 0);
        }

        // scale + mask: mrw pre-shifted by l15 -> bits at 0,16,32,48
#pragma unroll
        for (int r = 0; r < 4; ++r) {
            unsigned m0 = (unsigned)mrw[r];
            unsigned m1 = (unsigned)(mrw[r] >> 32);
            sacc[0][r] = (m0 & 1u)         ? sacc[0][r] * 0.125f : -1e30f;
            sacc[1][r] = ((m0 >> 16) & 1u) ? sacc[1][r] * 0.125f : -1e30f;
            sacc[2][r] = (m1 & 1u)         ? sacc[2][r] * 0.125f : -1e30f;
            sacc[3][r] = ((m1 >> 16) & 1u) ? sacc[3][r] * 0.125f : -1e30f;
        }

        // online softmax (row r lives on the 16 lanes of this quad)
#pragma unroll
        for (int r = 0; r < 4; ++r) {
            float rm = fmaxf(fmaxf(sacc[0][r], sacc[1][r]), fmaxf(sacc[2][r], sacc[3][r]));
            rm = fmaxf(rm, __shfl_xor(rm, 1));
            rm = fmaxf(rm, __shfl_xor(rm, 2));
            rm = fmaxf(rm, __shfl_xor(rm, 4));
            rm = fmaxf(rm, __shfl_xor(rm, 8));
            float mn = fmaxf(m_i[r], rm);
            float alpha = exp2f((m_i[r] - mn) * LOG2E);
            m_i[r] = mn;
            float rs = 0.f;
#pragma unroll
            for (int c = 0; c < 4; ++c) {
                float pv = exp2f((sacc[c][r] - mn) * LOG2E);
                sacc[c][r] = pv;
                rs += pv;
            }
            rs += __shfl_xor(rs, 1);
            rs += __shfl_xor(rs, 2);
            rs += __shfl_xor(rs, 4);
            rs += __shfl_xor(rs, 8);
            l_i[r] = l_i[r] * alpha + rs;
#pragma unroll
            for (int c = 0; c < 4; ++c) oacc[c][r] *= alpha;
        }

        // P: C-layout -> A-layout via wave-private LDS (no barrier needed)
#pragma unroll
        for (int c = 0; c < 4; ++c)
#pragma unroll
            for (int r = 0; r < 4; ++r) {
                union { __hip_bfloat16 h; bf16 b; } u;
                u.h = __float2bfloat16(sacc[c][r]);
                Ps[wid][quad * 4 + r][16 * c + l15] = u.b;
            }

        bf16x8 aP0 = *(const bf16x8*)(&Ps[wid][l15][quad * 8]);
        bf16x8 aP1 = *(const bf16x8*)(&Ps[wid][l15][32 + quad * 8]);
#pragma unroll
        for (int c = 0; c < 4; ++c) {
            const bf16* vp = Vt + ((size_t)b * DHEAD + 16 * c + l15) * SEQ + j0 + quad * 8;
            bf16x8 v0 = *(const bf16x8*)(vp);
            bf16x8 v1 = *(const bf16x8*)(vp + 32);
            oacc[c] = __builtin_amdgcn_mfma_f32_16x16x32_bf16(aP0, v0, oacc[c], 0, 0, 0);
            oacc[c] = __builtin_amdgcn_mfma_f32_16x16x32_bf16(aP1, v1, oacc[c], 0, 0, 0);
        }
    }

    // stash partials
#pragma unroll
    for (int c = 0; c < 4; ++c)
#pragma unroll
        for (int r = 0; r < 4; ++r)
            Om[wid][quad * 4 + r][16 * c + l15] = oacc[c][r];
    if (l15 == 0) {
#pragma unroll
        for (int r = 0; r < 4; ++r) {
            Mw[wid][quad * 4 + r] = m_i[r];
            Lw[wid][quad * 4 + r] = l_i[r];
        }
    }
    __syncthreads();

    // combine: 256 threads, 4 output floats each (16 rows x 64 cols)
    {
        int row = tid >> 4;
        int c0 = (tid & 15) * 4;
        float M = fmaxf(fmaxf(Mw[0][row], Mw[1][row]), fmaxf(Mw[2][row], Mw[3][row]));
        float sc0 = exp2f((Mw[0][row] - M) * LOG2E);
        float sc1 = exp2f((Mw[1][row] - M) * LOG2E);
        float sc2 = exp2f((Mw[2][row] - M) * LOG2E);
        float sc3 = exp2f((Mw[3][row] - M) * LOG2E);
        float L = Lw[0][row] * sc0 + Lw[1][row] * sc1 + Lw[2][row] * sc2 + Lw[3][row] * sc3;
        float invL = 1.0f / L;
        float4 o;
        float* op = (float*)&o;
#pragma unroll
        for (int e = 0; e < 4; ++e) {
            op[e] = (Om[0][row][c0 + e] * sc0 + Om[1][row][c0 + e] * sc1 +
                     Om[2][row][c0 + e] * sc2 + Om[3][row][c0 + e] * sc3) * invL;
        }
        *(float4*)(out + ((size_t)(b * SEQ + q0 + row)) * DHEAD + c0) = o;
    }
}

extern "C" void kernel_launch(void* const* d_in, const int* in_sizes, int n_in,
                              void* d_out, int out_size, void* d_ws, size_t ws_size,
                              hipStream_t stream)
{
    // setup_inputs order: mask, x_key_value, wk, wq, wv   (wk BEFORE wq!)
    const int*   mask = (const int*)d_in[0];
    const float* x    = (const float*)d_in[1];
    const float* wk   = (const float*)d_in[2];
    const float* wq   = (const float*)d_in[3];
    const float* wv   = (const float*)d_in[4];
    float* out = (float*)d_out;

    bf16* Qb = (bf16*)d_ws;
    bf16* Kb = Qb + (size_t)ROWS * DHEAD;
    bf16* Vt = Kb + (size_t)ROWS * DHEAD;
    bf16* Wt = Vt + (size_t)BATCH * DHEAD * SEQ;

    transpose_w_kernel<<<dim3(24), 256, 0, stream>>>(wq, wk, wv, Wt);
    proj_kernel<<<dim3(ROWS / 32), 512, 0, stream>>>(x, Wt, Qb, Kb, Vt);
    flash_kernel<<<dim3(SEQ / 16, BATCH), 256, 0, stream>>>(Qb, Kb, Vt, mask, out);
}

// Round 6
// 281.843 us; speedup vs baseline: 1.2749x; 1.0141x over previous
//
#include <hip/hip_runtime.h>
#include <hip/hip_bf16.h>

typedef __attribute__((ext_vector_type(8))) short bf16x8;
typedef __attribute__((ext_vector_type(4))) float f32x4;
typedef __hip_bfloat16 bf16;

#define BATCH 8
#define SEQ   2048
#define DMODEL 512
#define DHEAD 64
#define ROWS (BATCH * SEQ)
#define LOG2E 1.44269504f

static __device__ inline short f2bf(float f) {
    union { __hip_bfloat16 h; short s; } u;
    u.h = __float2bfloat16(f);
    return u.s;
}

// ---------------------------------------------------------------------------
// W transpose: w[512][64] fp32 -> wt[64][512] bf16, LDS-tiled, coalesced both
// sides. grid (3 sel x 8 k-tiles) = 24 blocks, block 256.
__global__ __launch_bounds__(256) void transpose_w_kernel(
    const float* __restrict__ wq, const float* __restrict__ wk,
    const float* __restrict__ wv, bf16* __restrict__ wt)
{
    const int s  = blockIdx.x / 8;       // 0:wq 1:wk 2:wv
    const int kt = blockIdx.x % 8;       // k-tile of 64
    const float* w = (s == 0) ? wq : ((s == 1) ? wk : wv);

    __shared__ float Ts[64][68];         // [k][n], +4 pad

    const int tid = threadIdx.x;
    int nr = tid >> 4;                   // 0..15
    int n4 = (tid & 15) * 4;
#pragma unroll
    for (int p = 0; p < 4; ++p) {
        int k = 16 * p + nr;
        float4 v = *(const float4*)(w + (size_t)(kt * 64 + k) * DHEAD + n4);
        Ts[k][n4] = v.x; Ts[k][n4 + 1] = v.y; Ts[k][n4 + 2] = v.z; Ts[k][n4 + 3] = v.w;
    }
    __syncthreads();
#pragma unroll
    for (int p = 0; p < 2; ++p) {
        int cc = tid + p * 256;          // 0..511
        int n = cc >> 3;
        int kk = (cc & 7) * 8;
        bf16x8 o;
#pragma unroll
        for (int e = 0; e < 8; ++e) o[e] = f2bf(Ts[kk + e][n]);
        *(bf16x8*)(wt + (size_t)(s * 64 + n) * DMODEL + kt * 64 + kk) = o;
    }
}

// ---------------------------------------------------------------------------
// Fused QKV projection. grid ROWS/32 = 512 blocks, block 512 (8 waves).
__global__ __launch_bounds__(512) void proj_kernel(
    const float* __restrict__ x, const bf16* __restrict__ wt,
    bf16* __restrict__ Q, bf16* __restrict__ K, bf16* __restrict__ Vt)
{
    const int r0 = blockIdx.x * 32;
    const int tid = threadIdx.x;
    const int lane = tid & 63;
    const int wid = tid >> 6;          // 0..7
    const int strip = wid & 1;
    const int cq = wid >> 1;           // 0..3
    const int l15 = lane & 15;
    const int quad = lane >> 4;

    f32x4 acc[3] = {};

    const float* xp = x + (size_t)(r0 + 16 * strip + l15) * DMODEL;

    for (int k0 = 0; k0 < DMODEL; k0 += 64) {
        float4 xa = *(const float4*)(xp + k0 + quad * 8);
        float4 xb = *(const float4*)(xp + k0 + quad * 8 + 4);
        float4 xc = *(const float4*)(xp + k0 + 32 + quad * 8);
        float4 xd = *(const float4*)(xp + k0 + 32 + quad * 8 + 4);
        bf16x8 a0, a1;
        a0[0] = f2bf(xa.x); a0[1] = f2bf(xa.y); a0[2] = f2bf(xa.z); a0[3] = f2bf(xa.w);
        a0[4] = f2bf(xb.x); a0[5] = f2bf(xb.y); a0[6] = f2bf(xb.z); a0[7] = f2bf(xb.w);
        a1[0] = f2bf(xc.x); a1[1] = f2bf(xc.y); a1[2] = f2bf(xc.z); a1[3] = f2bf(xc.w);
        a1[4] = f2bf(xd.x); a1[5] = f2bf(xd.y); a1[6] = f2bf(xd.z); a1[7] = f2bf(xd.w);
#pragma unroll
        for (int g = 0; g < 3; ++g) {
            int n = 16 * (3 * cq + g) + l15;
            const bf16* wp = wt + (size_t)n * DMODEL + k0 + quad * 8;
            bf16x8 b0 = *(const bf16x8*)(wp);
            bf16x8 b1 = *(const bf16x8*)(wp + 32);
            acc[g] = __builtin_amdgcn_mfma_f32_16x16x32_bf16(a0, b0, acc[g], 0, 0, 0);
            acc[g] = __builtin_amdgcn_mfma_f32_16x16x32_bf16(a1, b1, acc[g], 0, 0, 0);
        }
    }

#pragma unroll
    for (int g = 0; g < 3; ++g) {
        int ng = 16 * (3 * cq + g) + l15;   // 0..191
        int sel = ng >> 6;
        int col = ng & 63;
#pragma unroll
        for (int r = 0; r < 4; ++r) {
            int row = r0 + 16 * strip + quad * 4 + r;   // flat (b*SEQ + i)
            union { __hip_bfloat16 h; bf16 b; } u;
            u.h = __float2bfloat16(acc[g][r]);
            if (sel == 0)      Q[(size_t)row * DHEAD + col] = u.b;
            else if (sel == 1) K[(size_t)row * DHEAD + col] = u.b;
            else {
                int bb = row >> 11, j = row & (SEQ - 1);
                Vt[((size_t)bb * DHEAD + col) * SEQ + j] = u.b;
            }
        }
    }
}

// ---------------------------------------------------------------------------
// Flash attention, single-pass mask, register-pipelined — R6 fixes:
//
// (1) GRANULARITY: mask loaded as int4 (16 B/lane; 4 instr/round instead of
//     16 dword instrs). Every prior mask structure (R0/R2/R3/R5) used dword
//     loads and all plateaued at 0.83-1.17 TB/s — the 4 B/lane regime (G13).
//     Load shape: instr g, lane (quad,l15) -> row 4g+quad, cols 4*l15..+3
//     (4 x 256 B segments per instr).
// (2) DRAIN ORDER (in-order vmcnt): V is hoisted to the round top with K and
//     held in regs, so PV's wait is a counted vmcnt that leaves the mask
//     loads in flight. R5's PV-embedded V loads made every V-wait drain the
//     just-issued mask loads (~300 cyc cover instead of a full round).
//     Round: K+V loads -> QK^T (vmcnt drains K + round-old mask) ->
//     ballots -> issue next mask -> softmax -> P -> PV (counted wait).
//
// Bit plumbing: ballot_c over component c of group g packs bit (16q+m) =
// mask[row 4g+q][j 4m+c]. Consumer lane (quad,l15), row r=quad*4+r, col
// j=16c+l15: word = ballot_{l15&3}(group quad) >> (l15>>2); bit (16r+4c).
// One u64 per lane holds the whole 4x4 (row,col) gate. All selects are on
// NAMED scalars (R4 scratch lesson).
__global__ __launch_bounds__(256) void flash_kernel(
    const bf16* __restrict__ Q, const bf16* __restrict__ K,
    const bf16* __restrict__ Vt, const int* __restrict__ mask,
    float* __restrict__ out)
{
    const int b = blockIdx.y;
    const int q0 = blockIdx.x * 16;
    const int tid = threadIdx.x;
    const int lane = tid & 63;
    const int wid = tid >> 6;      // 0..3 = j-split index
    const int l15 = lane & 15;
    const int quad = lane >> 4;

    __shared__ __align__(16) bf16 Ps[4][16][72];    // wave-private P tiles
    __shared__ float Om[4][16][64];                 // partial O per wave
    __shared__ float Mw[4][16];                     // partial m per wave
    __shared__ float Lw[4][16];                     // partial l per wave

    const bf16* qp = Q + ((size_t)(b * SEQ + q0 + l15)) * DHEAD + quad * 8;
    bf16x8 aQ0 = *(const bf16x8*)(qp);
    bf16x8 aQ1 = *(const bf16x8*)(qp + 32);

    f32x4 oacc[4] = {};
    float m_i[4], l_i[4];
#pragma unroll
    for (int r = 0; r < 4; ++r) { m_i[r] = -1e30f; l_i[r] = 0.f; }

    const int jbase = wid * (SEQ / 4);
    // per-lane int4 mask base: row (4g+quad), col 4*l15 within this wave's j-range
    const int* mlane = mask + ((size_t)(b * SEQ + q0 + quad)) * SEQ + jbase + 4 * l15;

#define MLD(g, kkv) (*(const int4*)(mlane + (size_t)(4 * (g)) * SEQ + (kkv) * 64))

    // prologue: round-0 mask vectors (one exposed latency, once)
    int4 mva = MLD(0, 0), mvb = MLD(1, 0), mvc = MLD(2, 0), mvd = MLD(3, 0);

    for (int kk = 0; kk < 8; ++kk) {
        const int j0 = jbase + kk * 64;

        // K and V loads FIRST (both L2-resident). V held in regs until PV so
        // PV's wait is counted and does NOT drain the mask loads.
        bf16x8 kb[8], vr[8];
#pragma unroll
        for (int c = 0; c < 4; ++c) {
            const bf16* kp = K + ((size_t)(b * SEQ + j0 + 16 * c + l15)) * DHEAD + quad * 8;
            kb[2 * c]     = *(const bf16x8*)(kp);
            kb[2 * c + 1] = *(const bf16x8*)(kp + 32);
        }
#pragma unroll
        for (int c = 0; c < 4; ++c) {
            const bf16* vp = Vt + ((size_t)b * DHEAD + 16 * c + l15) * SEQ + j0 + quad * 8;
            vr[2 * c]     = *(const bf16x8*)(vp);
            vr[2 * c + 1] = *(const bf16x8*)(vp + 32);
        }
        __builtin_amdgcn_sched_barrier(0);

        // S = Q K^T. The kb-wait here is counted; it also drains the
        // round-old mask vectors (full-round cover).
        f32x4 sacc[4] = {};
#pragma unroll
        for (int c = 0; c < 4; ++c) {
            sacc[c] = __builtin_amdgcn_mfma_f32_16x16x32_bf16(aQ0, kb[2 * c],     sacc[c], 0, 0, 0);
            sacc[c] = __builtin_amdgcn_mfma_f32_16x16x32_bf16(aQ1, kb[2 * c + 1], sacc[c], 0, 0, 0);
        }
        __builtin_amdgcn_sched_barrier(0);

        // ballots (wave-uniform) from the round-old mask vectors
        unsigned long long B00 = __ballot(mva.x != 0), B01 = __ballot(mva.y != 0),
                           B02 = __ballot(mva.z != 0), B03 = __ballot(mva.w != 0);
        unsigned long long B10 = __ballot(mvb.x != 0), B11 = __ballot(mvb.y != 0),
                           B12 = __ballot(mvb.z != 0), B13 = __ballot(mvb.w != 0);
        unsigned long long B20 = __ballot(mvc.x != 0), B21 = __ballot(mvc.y != 0),
                           B22 = __ballot(mvc.z != 0), B23 = __ballot(mvc.w != 0);
        unsigned long long B30 = __ballot(mvd.x != 0), B31 = __ballot(mvd.y != 0),
                           B32 = __ballot(mvd.z != 0), B33 = __ballot(mvd.w != 0);

        // issue NEXT round's mask loads (consumed next iteration; stay in
        // flight through softmax+P+PV thanks to the counted PV wait)
        if (kk < 7) {
            mva = MLD(0, kk + 1); mvb = MLD(1, kk + 1);
            mvc = MLD(2, kk + 1); mvd = MLD(3, kk + 1);
        }
        __builtin_amdgcn_sched_barrier(0);

        // per-lane word select (named scalars only): group by quad, comp by l15&3
        unsigned long long c0g = (quad & 2) ? ((quad & 1) ? B30 : B20) : ((quad & 1) ? B10 : B00);
        unsigned long long c1g = (quad & 2) ? ((quad & 1) ? B31 : B21) : ((quad & 1) ? B11 : B01);
        unsigned long long c2g = (quad & 2) ? ((quad & 1) ? B32 : B22) : ((quad & 1) ? B12 : B02);
        unsigned long long c3g = (quad & 2) ? ((quad & 1) ? B33 : B23) : ((quad & 1) ? B13 : B03);
        unsigned long long s01 = (l15 & 1) ? c1g : c0g;
        unsigned long long s23 = (l15 & 1) ? c3g : c2g;
        unsigned long long wsel = ((l15 & 2) ? s23 : s01) >> (l15 >> 2);
        unsigned wlo = (unsigned)wsel;
        unsigned whi = (unsigned)(wsel >> 32);

        // scale + mask: bit (16r + 4c) of wsel  (r<2 -> lo, r>=2 -> hi)
#pragma unroll
        for (int c = 0; c < 4; ++c) {
            sacc[c][0] = ((wlo >> (4 * c))      & 1u) ? sacc[c][0] * 0.125f : -1e30f;
            sacc[c][1] = ((wlo >> (16 + 4 * c)) & 1u) ? sacc[c][1] * 0.125f : -1e30f;
            sacc[c][2] = ((whi >> (4 * c))      & 1u) ? sacc[c][2] * 0.125f : -1e30f;
            sacc[c][3] = ((whi >> (16 + 4 * c)) & 1u) ? sacc[c][3] * 0.125f : -1e30f;
        }

        // online softmax (row r lives on the 16 lanes of this quad)
#pragma unroll
        for (int r = 0; r < 4; ++r) {
            float rm = fmaxf(fmaxf(sacc[0][r], sacc[1][r]), fmaxf(sacc[2][r], sacc[3][r]));
            rm = fmaxf(rm, __shfl_xor(rm, 1));
            rm = fmaxf(rm, __shfl_xor(rm, 2));
            rm = fmaxf(rm, __shfl_xor(rm, 4));
            rm = fmaxf(rm, __shfl_xor(rm, 8));
            float mn = fmaxf(m_i[r], rm);
            float alpha = exp2f((m_i[r] - mn) * LOG2E);
            m_i[r] = mn;
            float rs = 0.f;
#pragma unroll
            for (int c = 0; c < 4; ++c) {
                float pv = exp2f((sacc[c][r] - mn) * LOG2E);
                sacc[c][r] = pv;
                rs += pv;
            }
            rs += __shfl_xor(rs, 1);
            rs += __shfl_xor(rs, 2);
            rs += __shfl_xor(rs, 4);
            rs += __shfl_xor(rs, 8);
            l_i[r] = l_i[r] * alpha + rs;
#pragma unroll
            for (int c = 0; c < 4; ++c) oacc[c][r] *= alpha;
        }

        // P: C-layout -> A-layout via wave-private LDS (no barrier needed)
#pragma unroll
        for (int c = 0; c < 4; ++c)
#pragma unroll
            for (int r = 0; r < 4; ++r) {
                union { __hip_bfloat16 h; bf16 b; } u;
                u.h = __float2bfloat16(sacc[c][r]);
                Ps[wid][quad * 4 + r][16 * c + l15] = u.b;
            }

        bf16x8 aP0 = *(const bf16x8*)(&Ps[wid][l15][quad * 8]);
        bf16x8 aP1 = *(const bf16x8*)(&Ps[wid][l15][32 + quad * 8]);
#pragma unroll
        for (int c = 0; c < 4; ++c) {
            oacc[c] = __builtin_amdgcn_mfma_f32_16x16x32_bf16(aP0, vr[2 * c],     oacc[c], 0, 0, 0);
            oacc[c] = __builtin_amdgcn_mfma_f32_16x16x32_bf16(aP1, vr[2 * c + 1], oacc[c], 0, 0, 0);
        }
    }
#undef MLD

    // stash partials
#pragma unroll
    for (int c = 0; c < 4; ++c)
#pragma unroll
        for (int r = 0; r < 4; ++r)
            Om[wid][quad * 4 + r][16 * c + l15] = oacc[c][r];
    if (l15 == 0) {
#pragma unroll
        for (int r = 0; r < 4; ++r) {
            Mw[wid][quad * 4 + r] = m_i[r];
            Lw[wid][quad * 4 + r] = l_i[r];
        }
    }
    __syncthreads();

    // combine: 256 threads, 4 output floats each (16 rows x 64 cols)
    {
        int row = tid >> 4;
        int c0 = (tid & 15) * 4;
        float M = fmaxf(fmaxf(Mw[0][row], Mw[1][row]), fmaxf(Mw[2][row], Mw[3][row]));
        float sc0 = exp2f((Mw[0][row] - M) * LOG2E);
        float sc1 = exp2f((Mw[1][row] - M) * LOG2E);
        float sc2 = exp2f((Mw[2][row] - M) * LOG2E);
        float sc3 = exp2f((Mw[3][row] - M) * LOG2E);
        float L = Lw[0][row] * sc0 + Lw[1][row] * sc1 + Lw[2][row] * sc2 + Lw[3][row] * sc3;
        float invL = 1.0f / L;
        float4 o;
        float* op = (float*)&o;
#pragma unroll
        for (int e = 0; e < 4; ++e) {
            op[e] = (Om[0][row][c0 + e] * sc0 + Om[1][row][c0 + e] * sc1 +
                     Om[2][row][c0 + e] * sc2 + Om[3][row][c0 + e] * sc3) * invL;
        }
        *(float4*)(out + ((size_t)(b * SEQ + q0 + row)) * DHEAD + c0) = o;
    }
}

extern "C" void kernel_launch(void* const* d_in, const int* in_sizes, int n_in,
                              void* d_out, int out_size, void* d_ws, size_t ws_size,
                              hipStream_t stream)
{
    // setup_inputs order: mask, x_key_value, wk, wq, wv   (wk BEFORE wq!)
    const int*   mask = (const int*)d_in[0];
    const float* x    = (const float*)d_in[1];
    const float* wk   = (const float*)d_in[2];
    const float* wq   = (const float*)d_in[3];
    const float* wv   = (const float*)d_in[4];
    float* out = (float*)d_out;

    bf16* Qb = (bf16*)d_ws;
    bf16* Kb = Qb + (size_t)ROWS * DHEAD;
    bf16* Vt = Kb + (size_t)ROWS * DHEAD;
    bf16* Wt = Vt + (size_t)BATCH * DHEAD * SEQ;

    transpose_w_kernel<<<dim3(24), 256, 0, stream>>>(wq, wk, wv, Wt);
    proj_kernel<<<dim3(ROWS / 32), 512, 0, stream>>>(x, Wt, Qb, Kb, Vt);
    flash_kernel<<<dim3(SEQ / 16, BATCH), 256, 0, stream>>>(Qb, Kb, Vt, mask, out);
}